// Round 5
// baseline (372.100 us; speedup 1.0000x reference)
//
#include <hip/hip_runtime.h>

#define LN_EPS 1e-5f
#define C_M 256
#define C_Z 128
#define NO_BINS 15

typedef float f4 __attribute__((ext_vector_type(4)));

__device__ __forceinline__ f4 f4zero() { f4 t = {0.f, 0.f, 0.f, 0.f}; return t; }

// one-hot bin index (or -1); strict inequalities; numpy f32 op order (no FMA)
__device__ __forceinline__ int bin_of_xj(const float* __restrict__ x,
                                         const float* sqb, int i,
                                         float xj0, float xj1, float xj2)
{
    const float dx = x[3 * i + 0] - xj0;
    const float dy = x[3 * i + 1] - xj1;
    const float dz = x[3 * i + 2] - xj2;
    const float d = __fadd_rn(__fadd_rn(__fmul_rn(dx, dx), __fmul_rn(dy, dy)),
                              __fmul_rn(dz, dz));
    int cnt = 0;
#pragma unroll
    for (int k = 0; k < NO_BINS; ++k) {
        const float bk = 3.25f + 1.25f * (float)k;
        cnt += (d > bk * bk) ? 1 : 0;
    }
    // boundary equality d == sq[cnt] zeroes the one-hot (sqb[15] = -1 sentinel)
    return ((cnt > 0) && (d < 1e8f) && (d != sqb[cnt])) ? cnt - 1 : -1;
}

__device__ __forceinline__ void ln_stats(const f4 v, float& s, float& s2)
{
    s  = v.x + v.y + v.z + v.w;
    s2 = v.x * v.x + v.y * v.y + v.z * v.z + v.w * v.w;
}

// process 4 rows (already loaded): bins, LDS gather, LN, store
__device__ __forceinline__ void process4(
    f4 v0, f4 v1, f4 v2, f4 v3,
    const float* __restrict__ x, const float* sqb, const float* lw,
    int i, float xj0, float xj1, float xj2,
    const f4 wv, const f4 bv, float* __restrict__ out_z,
    long long r, long long S, int lane)
{
    const int b0 = bin_of_xj(x, sqb, i,      xj0, xj1, xj2);
    const int b1 = bin_of_xj(x, sqb, i + 16, xj0, xj1, xj2);
    const int b2 = bin_of_xj(x, sqb, i + 32, xj0, xj1, xj2);
    const int b3 = bin_of_xj(x, sqb, i + 48, xj0, xj1, xj2);

    f4 e0 = f4zero(), e1 = f4zero(), e2 = f4zero(), e3 = f4zero();
    if (b0 >= 0) e0 = reinterpret_cast<const f4*>(lw + b0 * C_Z)[lane];
    if (b1 >= 0) e1 = reinterpret_cast<const f4*>(lw + b1 * C_Z)[lane];
    if (b2 >= 0) e2 = reinterpret_cast<const f4*>(lw + b2 * C_Z)[lane];
    if (b3 >= 0) e3 = reinterpret_cast<const f4*>(lw + b3 * C_Z)[lane];

    float s0, q0, s1, q1, s2, q2, s3, q3;
    ln_stats(v0, s0, q0); ln_stats(v1, s1, q1);
    ln_stats(v2, s2, q2); ln_stats(v3, s3, q3);
#pragma unroll
    for (int msk = 1; msk < 32; msk <<= 1) {   // stays within the 32-lane group
        s0 += __shfl_xor(s0, msk); q0 += __shfl_xor(q0, msk);
        s1 += __shfl_xor(s1, msk); q1 += __shfl_xor(q1, msk);
        s2 += __shfl_xor(s2, msk); q2 += __shfl_xor(q2, msk);
        s3 += __shfl_xor(s3, msk); q3 += __shfl_xor(q3, msk);
    }
    const float mu0 = s0 * (1.0f / C_Z), iv0 = rsqrtf(q0 * (1.0f / C_Z) - mu0 * mu0 + LN_EPS);
    const float mu1 = s1 * (1.0f / C_Z), iv1 = rsqrtf(q1 * (1.0f / C_Z) - mu1 * mu1 + LN_EPS);
    const float mu2 = s2 * (1.0f / C_Z), iv2 = rsqrtf(q2 * (1.0f / C_Z) - mu2 * mu2 + LN_EPS);
    const float mu3 = s3 * (1.0f / C_Z), iv3 = rsqrtf(q3 * (1.0f / C_Z) - mu3 * mu3 + LN_EPS);

    f4 o0 = (v0 - mu0) * iv0 * wv + bv + e0;
    f4 o1 = (v1 - mu1) * iv1 * wv + bv + e1;
    f4 o2 = (v2 - mu2) * iv2 * wv + bv + e2;
    f4 o3 = (v3 - mu3) * iv3 * wv + bv + e3;
    __builtin_nontemporal_store(o0, reinterpret_cast<f4*>(out_z + r * C_Z) + lane);
    __builtin_nontemporal_store(o1, reinterpret_cast<f4*>(out_z + (r + S) * C_Z) + lane);
    __builtin_nontemporal_store(o2, reinterpret_cast<f4*>(out_z + (r + 2 * S) * C_Z) + lane);
    __builtin_nontemporal_store(o3, reinterpret_cast<f4*>(out_z + (r + 3 * S) * C_Z) + lane);
}

// ---- pipelined fused kernel: requires N%64==0, grid = 2N blocks ----
// slot = bid*8+half in [0,16N); rows slot + t*16N, t in [0,N/16)
// i = slot/N + 16t, j = slot%N constant. 4-row phases, A/B prefetch pipeline.
__global__ __launch_bounds__(256, 6) void fused_pipe(
    const float* __restrict__ m, const float* __restrict__ ln_m_w,
    const float* __restrict__ ln_m_b, float* __restrict__ out_m, int m_rows,
    const float* __restrict__ z, const float* __restrict__ x,
    const float* __restrict__ lin_w, const float* __restrict__ lin_b,
    const float* __restrict__ ln_z_w, const float* __restrict__ ln_z_b,
    float* __restrict__ out_z, int N, int phases)
{
    __shared__ float lw[NO_BINS * C_Z];   // transposed: [bin][c]
    __shared__ float sqb[16];
    const int tid = threadIdx.x;
    for (int t = tid; t < NO_BINS * C_Z; t += 256) {
        const int c = t / NO_BINS;
        const int bin = t - c * NO_BINS;
        lw[bin * C_Z + c] = lin_w[t];
    }
    if (tid < 16) {
        const float bk = 3.25f + 1.25f * (float)tid;
        sqb[tid] = (tid < NO_BINS) ? bk * bk : -1.0f;
    }
    __syncthreads();

    // ---- m LayerNorm: first ceil(m_rows/4) blocks, one wave per row ----
    if ((int)blockIdx.x < ((m_rows + 3) >> 2)) {
        const int wid    = tid >> 6;
        const int lane64 = tid & 63;
        const int row    = blockIdx.x * 4 + wid;
        if (row < m_rows) {
            const f4 v = reinterpret_cast<const f4*>(m + (long long)row * C_M)[lane64];
            float s, s2; ln_stats(v, s, s2);
#pragma unroll
            for (int msk = 1; msk < 64; msk <<= 1) {
                s  += __shfl_xor(s,  msk);
                s2 += __shfl_xor(s2, msk);
            }
            const float mu  = s * (1.0f / C_M);
            const float inv = rsqrtf(s2 * (1.0f / C_M) - mu * mu + LN_EPS);
            const f4 wv = reinterpret_cast<const f4*>(ln_m_w)[lane64];
            const f4 bv = reinterpret_cast<const f4*>(ln_m_b)[lane64];
            f4 o = (v - mu) * inv * wv + bv;
            reinterpret_cast<f4*>(out_m + (long long)row * C_M)[lane64] = o;
        }
    }

    // ---- z loop, software-pipelined ----
    const int half = tid >> 5;
    const int lane = tid & 31;

    const f4 wv = reinterpret_cast<const f4*>(ln_z_w)[lane];
    f4 bv = reinterpret_cast<const f4*>(ln_z_b)[lane];
    bv += reinterpret_cast<const f4*>(lin_b)[lane];   // fold lin_b

    const int slot = (int)blockIdx.x * 8 + half;      // [0, 16N)
    const long long S = (long long)N * 16;            // row stride per t
    int i = slot / N;                                 // [0,16)
    const int j = slot - i * N;

    const float xj0 = x[3 * j + 0];
    const float xj1 = x[3 * j + 1];
    const float xj2 = x[3 * j + 2];

    long long r = slot;

    // prologue: load phase-0 rows
    f4 a0 = reinterpret_cast<const f4*>(z + r * C_Z)[lane];
    f4 a1 = reinterpret_cast<const f4*>(z + (r + S) * C_Z)[lane];
    f4 a2 = reinterpret_cast<const f4*>(z + (r + 2 * S) * C_Z)[lane];
    f4 a3 = reinterpret_cast<const f4*>(z + (r + 3 * S) * C_Z)[lane];

    for (int p = 0; p < phases; p += 2) {
        f4 b0 = f4zero(), b1 = f4zero(), b2 = f4zero(), b3 = f4zero();
        const bool hasB = (p + 1) < phases;
        if (hasB) {   // prefetch phase p+1 BEFORE processing phase p
            b0 = reinterpret_cast<const f4*>(z + (r + 4 * S) * C_Z)[lane];
            b1 = reinterpret_cast<const f4*>(z + (r + 5 * S) * C_Z)[lane];
            b2 = reinterpret_cast<const f4*>(z + (r + 6 * S) * C_Z)[lane];
            b3 = reinterpret_cast<const f4*>(z + (r + 7 * S) * C_Z)[lane];
        }
        process4(a0, a1, a2, a3, x, sqb, lw, i, xj0, xj1, xj2,
                 wv, bv, out_z, r, S, lane);
        if (hasB) {
            if ((p + 2) < phases) {   // prefetch phase p+2 before processing p+1
                a0 = reinterpret_cast<const f4*>(z + (r + 8 * S) * C_Z)[lane];
                a1 = reinterpret_cast<const f4*>(z + (r + 9 * S) * C_Z)[lane];
                a2 = reinterpret_cast<const f4*>(z + (r + 10 * S) * C_Z)[lane];
                a3 = reinterpret_cast<const f4*>(z + (r + 11 * S) * C_Z)[lane];
            }
            process4(b0, b1, b2, b3, x, sqb, lw, i + 64, xj0, xj1, xj2,
                     wv, bv, out_z, r + 4 * S, S, lane);
        }
        r += 8 * S;
        i += 128;
    }
}

// ---- generic fallback (any N) ----
__device__ __forceinline__ int bin_of(const float* __restrict__ x,
                                      const float* sqb, int i, int j)
{
    return bin_of_xj(x, sqb, i, x[3 * j], x[3 * j + 1], x[3 * j + 2]);
}

__global__ __launch_bounds__(256) void fused_generic(
    const float* __restrict__ m, const float* __restrict__ ln_m_w,
    const float* __restrict__ ln_m_b, float* __restrict__ out_m, int m_rows,
    const float* __restrict__ z, const float* __restrict__ x,
    const float* __restrict__ lin_w, const float* __restrict__ lin_b,
    const float* __restrict__ ln_z_w, const float* __restrict__ ln_z_b,
    float* __restrict__ out_z, int N)
{
    __shared__ float lw[NO_BINS * C_Z];
    __shared__ float sqb[16];
    const int tid = threadIdx.x;
    for (int t = tid; t < NO_BINS * C_Z; t += 256) {
        const int c = t / NO_BINS;
        const int bin = t - c * NO_BINS;
        lw[bin * C_Z + c] = lin_w[t];
    }
    if (tid < 16) {
        const float bk = 3.25f + 1.25f * (float)tid;
        sqb[tid] = (tid < NO_BINS) ? bk * bk : -1.0f;
    }
    __syncthreads();

    if ((int)blockIdx.x < ((m_rows + 3) >> 2)) {
        const int wid    = tid >> 6;
        const int lane64 = tid & 63;
        const int row    = blockIdx.x * 4 + wid;
        if (row < m_rows) {
            const f4 v = reinterpret_cast<const f4*>(m + (long long)row * C_M)[lane64];
            float s, s2; ln_stats(v, s, s2);
#pragma unroll
            for (int msk = 1; msk < 64; msk <<= 1) {
                s  += __shfl_xor(s,  msk);
                s2 += __shfl_xor(s2, msk);
            }
            const float mu  = s * (1.0f / C_M);
            const float inv = rsqrtf(s2 * (1.0f / C_M) - mu * mu + LN_EPS);
            const f4 wv = reinterpret_cast<const f4*>(ln_m_w)[lane64];
            const f4 bv = reinterpret_cast<const f4*>(ln_m_b)[lane64];
            f4 o = (v - mu) * inv * wv + bv;
            reinterpret_cast<f4*>(out_m + (long long)row * C_M)[lane64] = o;
        }
    }

    const int half = tid >> 5;
    const int lane = tid & 31;
    const f4 wv = reinterpret_cast<const f4*>(ln_z_w)[lane];
    f4 bv = reinterpret_cast<const f4*>(ln_z_b)[lane];
    bv += reinterpret_cast<const f4*>(lin_b)[lane];

    const long long total  = (long long)N * N;
    const long long stride = (long long)gridDim.x * 8;
    for (long long r = (long long)blockIdx.x * 8 + half; r < total; r += stride) {
        const int i = (int)(r / N);
        const int j = (int)(r - (long long)i * N);
        const f4 v = reinterpret_cast<const f4*>(z + r * C_Z)[lane];
        const int bin = bin_of(x, sqb, i, j);
        f4 e = f4zero();
        if (bin >= 0) e = reinterpret_cast<const f4*>(lw + bin * C_Z)[lane];
        float s, s2; ln_stats(v, s, s2);
#pragma unroll
        for (int msk = 1; msk < 32; msk <<= 1) {
            s  += __shfl_xor(s,  msk);
            s2 += __shfl_xor(s2, msk);
        }
        const float mu  = s * (1.0f / C_Z);
        const float inv = rsqrtf(s2 * (1.0f / C_Z) - mu * mu + LN_EPS);
        f4 o = (v - mu) * inv * wv + bv + e;
        __builtin_nontemporal_store(o, reinterpret_cast<f4*>(out_z + r * C_Z) + lane);
    }
}

extern "C" void kernel_launch(void* const* d_in, const int* in_sizes, int n_in,
                              void* d_out, int out_size, void* d_ws, size_t ws_size,
                              hipStream_t stream) {
    const float* m      = (const float*)d_in[0];
    const float* z      = (const float*)d_in[1];
    const float* x      = (const float*)d_in[2];
    // d_in[3] = seqs (unused)
    const float* lin_w  = (const float*)d_in[4];
    const float* lin_b  = (const float*)d_in[5];
    const float* ln_m_w = (const float*)d_in[6];
    const float* ln_m_b = (const float*)d_in[7];
    const float* ln_z_w = (const float*)d_in[8];
    const float* ln_z_b = (const float*)d_in[9];

    const int N = in_sizes[0] / C_M;          // 768
    float* out_m = (float*)d_out;
    float* out_z = out_m + (long long)N * C_M;

    if ((N % 64) == 0 && 2 * N >= (N + 3) / 4) {
        // grid = 2N blocks (6/CU at N=768, co-resident), phases = N/64
        fused_pipe<<<2 * N, 256, 0, stream>>>(m, ln_m_w, ln_m_b, out_m, N,
                                              z, x, lin_w, lin_b, ln_z_w, ln_z_b,
                                              out_z, N, N / 64);
    } else {
        int g = 2048;
        const int mB = (N + 3) / 4;
        if (g < mB) g = mB;
        fused_generic<<<g, 256, 0, stream>>>(m, ln_m_w, ln_m_b, out_m, N,
                                             z, x, lin_w, lin_b, ln_z_w, ln_z_b,
                                             out_z, N);
    }
}

// Round 6
// 149.854 us; speedup vs baseline: 2.4831x; 2.4831x over previous
//
#include <hip/hip_runtime.h>

#define LN_EPS 1e-5f
#define C_M 256
#define C_Z 128
#define NO_BINS 15

typedef float f4 __attribute__((ext_vector_type(4)));

__device__ __forceinline__ f4 f4zero() { f4 t = {0.f, 0.f, 0.f, 0.f}; return t; }

// one-hot bin index (or -1); strict inequalities; numpy f32 op order (no FMA)
__device__ __forceinline__ int bin_of(const float* __restrict__ x,
                                      const float* sqb, int i, int j)
{
    const float dx = x[3 * i + 0] - x[3 * j + 0];
    const float dy = x[3 * i + 1] - x[3 * j + 1];
    const float dz = x[3 * i + 2] - x[3 * j + 2];
    const float d = __fadd_rn(__fadd_rn(__fmul_rn(dx, dx), __fmul_rn(dy, dy)),
                              __fmul_rn(dz, dz));
    int cnt = 0;
#pragma unroll
    for (int k = 0; k < NO_BINS; ++k) {
        const float bk = 3.25f + 1.25f * (float)k;
        cnt += (d > bk * bk) ? 1 : 0;
    }
    // boundary equality d == sq[cnt] zeroes the one-hot (sqb[15] = -1 sentinel)
    return ((cnt > 0) && (d < 1e8f) && (d != sqb[cnt])) ? cnt - 1 : -1;
}

__device__ __forceinline__ void ln_stats(const f4 v, float& s, float& s2)
{
    s  = v.x + v.y + v.z + v.w;
    s2 = v.x * v.x + v.y * v.y + v.z * v.z + v.w * v.w;
}

// ---- fused kernel, full occupancy: grid = 2048 blocks (8/CU, 32 waves/CU) --
// slot = bid*8+half in [0, 16384); rows r = slot + t*16384, t in [0, phases)
// (i,j) advanced incrementally by (di, rem) with wrap; phases*16384 == N*N.
__global__ __launch_bounds__(256, 8) void fused_occ(
    const float* __restrict__ m, const float* __restrict__ ln_m_w,
    const float* __restrict__ ln_m_b, float* __restrict__ out_m, int m_rows,
    const float* __restrict__ z, const float* __restrict__ x,
    const float* __restrict__ lin_w, const float* __restrict__ lin_b,
    const float* __restrict__ ln_z_w, const float* __restrict__ ln_z_b,
    float* __restrict__ out_z, int N, int phases, int di, int rem)
{
    __shared__ float lw[NO_BINS * C_Z];   // transposed: [bin][c]
    __shared__ float sqb[16];
    const int tid = threadIdx.x;
    for (int t = tid; t < NO_BINS * C_Z; t += 256) {
        const int c = t / NO_BINS;
        const int bin = t - c * NO_BINS;
        lw[bin * C_Z + c] = lin_w[t];
    }
    if (tid < 16) {
        const float bk = 3.25f + 1.25f * (float)tid;
        sqb[tid] = (tid < NO_BINS) ? bk * bk : -1.0f;
    }
    __syncthreads();

    // ---- m LayerNorm: first ceil(m_rows/4) blocks, one wave per row ----
    if ((int)blockIdx.x < ((m_rows + 3) >> 2)) {
        const int wid    = tid >> 6;
        const int lane64 = tid & 63;
        const int row    = blockIdx.x * 4 + wid;
        if (row < m_rows) {
            const f4 v = reinterpret_cast<const f4*>(m + (long long)row * C_M)[lane64];
            float s, s2; ln_stats(v, s, s2);
#pragma unroll
            for (int msk = 1; msk < 64; msk <<= 1) {
                s  += __shfl_xor(s,  msk);
                s2 += __shfl_xor(s2, msk);
            }
            const float mu  = s * (1.0f / C_M);
            const float inv = rsqrtf(s2 * (1.0f / C_M) - mu * mu + LN_EPS);
            const f4 wv = reinterpret_cast<const f4*>(ln_m_w)[lane64];
            const f4 bv = reinterpret_cast<const f4*>(ln_m_b)[lane64];
            f4 o = (v - mu) * inv * wv + bv;
            reinterpret_cast<f4*>(out_m + (long long)row * C_M)[lane64] = o;
        }
    }

    // ---- z loop: 4-row phases, incremental (i,j) ----
    const int half = tid >> 5;
    const int lane = tid & 31;

    const f4 wv = reinterpret_cast<const f4*>(ln_z_w)[lane];
    f4 bv = reinterpret_cast<const f4*>(ln_z_b)[lane];
    bv += reinterpret_cast<const f4*>(lin_b)[lane];   // fold lin_b

    const int slot = (int)blockIdx.x * 8 + half;      // [0, 16384)
    const long long S = (long long)gridDim.x * 8;     // rows per phase step
    int i = slot / N;
    int j = slot - i * N;

    long long r = slot;
    for (int p = 0; p < phases; p += 4) {
        // per-phase (i,j) for the 4 unrolled rows
        const int i0 = i, j0 = j;
        int i1 = i0 + di, j1 = j0 + rem; if (j1 >= N) { j1 -= N; ++i1; }
        int i2 = i1 + di, j2 = j1 + rem; if (j2 >= N) { j2 -= N; ++i2; }
        int i3 = i2 + di, j3 = j2 + rem; if (j3 >= N) { j3 -= N; ++i3; }
        i = i3 + di; j = j3 + rem; if (j >= N) { j -= N; ++i; }

        const long long r0 = r, r1 = r + S, r2 = r + 2 * S, r3 = r + 3 * S;

        const f4 v0 = reinterpret_cast<const f4*>(z + r0 * C_Z)[lane];
        const f4 v1 = reinterpret_cast<const f4*>(z + r1 * C_Z)[lane];
        const f4 v2 = reinterpret_cast<const f4*>(z + r2 * C_Z)[lane];
        const f4 v3 = reinterpret_cast<const f4*>(z + r3 * C_Z)[lane];

        const int b0 = bin_of(x, sqb, i0, j0);
        const int b1 = bin_of(x, sqb, i1, j1);
        const int b2 = bin_of(x, sqb, i2, j2);
        const int b3 = bin_of(x, sqb, i3, j3);

        f4 e0 = f4zero(), e1 = f4zero(), e2 = f4zero(), e3 = f4zero();
        if (b0 >= 0) e0 = reinterpret_cast<const f4*>(lw + b0 * C_Z)[lane];
        if (b1 >= 0) e1 = reinterpret_cast<const f4*>(lw + b1 * C_Z)[lane];
        if (b2 >= 0) e2 = reinterpret_cast<const f4*>(lw + b2 * C_Z)[lane];
        if (b3 >= 0) e3 = reinterpret_cast<const f4*>(lw + b3 * C_Z)[lane];

        float s0, q0, s1, q1, s2, q2, s3, q3;
        ln_stats(v0, s0, q0); ln_stats(v1, s1, q1);
        ln_stats(v2, s2, q2); ln_stats(v3, s3, q3);
#pragma unroll
        for (int msk = 1; msk < 32; msk <<= 1) {   // stays within 32-lane group
            s0 += __shfl_xor(s0, msk); q0 += __shfl_xor(q0, msk);
            s1 += __shfl_xor(s1, msk); q1 += __shfl_xor(q1, msk);
            s2 += __shfl_xor(s2, msk); q2 += __shfl_xor(q2, msk);
            s3 += __shfl_xor(s3, msk); q3 += __shfl_xor(q3, msk);
        }
        const float mu0 = s0 * (1.0f / C_Z), iv0 = rsqrtf(q0 * (1.0f / C_Z) - mu0 * mu0 + LN_EPS);
        const float mu1 = s1 * (1.0f / C_Z), iv1 = rsqrtf(q1 * (1.0f / C_Z) - mu1 * mu1 + LN_EPS);
        const float mu2 = s2 * (1.0f / C_Z), iv2 = rsqrtf(q2 * (1.0f / C_Z) - mu2 * mu2 + LN_EPS);
        const float mu3 = s3 * (1.0f / C_Z), iv3 = rsqrtf(q3 * (1.0f / C_Z) - mu3 * mu3 + LN_EPS);

        f4 o0 = (v0 - mu0) * iv0 * wv + bv + e0;
        f4 o1 = (v1 - mu1) * iv1 * wv + bv + e1;
        f4 o2 = (v2 - mu2) * iv2 * wv + bv + e2;
        f4 o3 = (v3 - mu3) * iv3 * wv + bv + e3;
        __builtin_nontemporal_store(o0, reinterpret_cast<f4*>(out_z + r0 * C_Z) + lane);
        __builtin_nontemporal_store(o1, reinterpret_cast<f4*>(out_z + r1 * C_Z) + lane);
        __builtin_nontemporal_store(o2, reinterpret_cast<f4*>(out_z + r2 * C_Z) + lane);
        __builtin_nontemporal_store(o3, reinterpret_cast<f4*>(out_z + r3 * C_Z) + lane);

        r += 4 * S;
    }
}

// ---- generic fallback (any N) ----
__global__ __launch_bounds__(256) void fused_generic(
    const float* __restrict__ m, const float* __restrict__ ln_m_w,
    const float* __restrict__ ln_m_b, float* __restrict__ out_m, int m_rows,
    const float* __restrict__ z, const float* __restrict__ x,
    const float* __restrict__ lin_w, const float* __restrict__ lin_b,
    const float* __restrict__ ln_z_w, const float* __restrict__ ln_z_b,
    float* __restrict__ out_z, int N)
{
    __shared__ float lw[NO_BINS * C_Z];
    __shared__ float sqb[16];
    const int tid = threadIdx.x;
    for (int t = tid; t < NO_BINS * C_Z; t += 256) {
        const int c = t / NO_BINS;
        const int bin = t - c * NO_BINS;
        lw[bin * C_Z + c] = lin_w[t];
    }
    if (tid < 16) {
        const float bk = 3.25f + 1.25f * (float)tid;
        sqb[tid] = (tid < NO_BINS) ? bk * bk : -1.0f;
    }
    __syncthreads();

    if ((int)blockIdx.x < ((m_rows + 3) >> 2)) {
        const int wid    = tid >> 6;
        const int lane64 = tid & 63;
        const int row    = blockIdx.x * 4 + wid;
        if (row < m_rows) {
            const f4 v = reinterpret_cast<const f4*>(m + (long long)row * C_M)[lane64];
            float s, s2; ln_stats(v, s, s2);
#pragma unroll
            for (int msk = 1; msk < 64; msk <<= 1) {
                s  += __shfl_xor(s,  msk);
                s2 += __shfl_xor(s2, msk);
            }
            const float mu  = s * (1.0f / C_M);
            const float inv = rsqrtf(s2 * (1.0f / C_M) - mu * mu + LN_EPS);
            const f4 wv = reinterpret_cast<const f4*>(ln_m_w)[lane64];
            const f4 bv = reinterpret_cast<const f4*>(ln_m_b)[lane64];
            f4 o = (v - mu) * inv * wv + bv;
            reinterpret_cast<f4*>(out_m + (long long)row * C_M)[lane64] = o;
        }
    }

    const int half = tid >> 5;
    const int lane = tid & 31;
    const f4 wv = reinterpret_cast<const f4*>(ln_z_w)[lane];
    f4 bv = reinterpret_cast<const f4*>(ln_z_b)[lane];
    bv += reinterpret_cast<const f4*>(lin_b)[lane];

    const long long total  = (long long)N * N;
    const long long stride = (long long)gridDim.x * 8;
    for (long long r = (long long)blockIdx.x * 8 + half; r < total; r += stride) {
        const int i = (int)(r / N);
        const int j = (int)(r - (long long)i * N);
        const f4 v = reinterpret_cast<const f4*>(z + r * C_Z)[lane];
        const int bin = bin_of(x, sqb, i, j);
        f4 e = f4zero();
        if (bin >= 0) e = reinterpret_cast<const f4*>(lw + bin * C_Z)[lane];
        float s, s2; ln_stats(v, s, s2);
#pragma unroll
        for (int msk = 1; msk < 32; msk <<= 1) {
            s  += __shfl_xor(s,  msk);
            s2 += __shfl_xor(s2, msk);
        }
        const float mu  = s * (1.0f / C_Z);
        const float inv = rsqrtf(s2 * (1.0f / C_Z) - mu * mu + LN_EPS);
        f4 o = (v - mu) * inv * wv + bv + e;
        __builtin_nontemporal_store(o, reinterpret_cast<f4*>(out_z + r * C_Z) + lane);
    }
}

extern "C" void kernel_launch(void* const* d_in, const int* in_sizes, int n_in,
                              void* d_out, int out_size, void* d_ws, size_t ws_size,
                              hipStream_t stream) {
    const float* m      = (const float*)d_in[0];
    const float* z      = (const float*)d_in[1];
    const float* x      = (const float*)d_in[2];
    // d_in[3] = seqs (unused)
    const float* lin_w  = (const float*)d_in[4];
    const float* lin_b  = (const float*)d_in[5];
    const float* ln_m_w = (const float*)d_in[6];
    const float* ln_m_b = (const float*)d_in[7];
    const float* ln_z_w = (const float*)d_in[8];
    const float* ln_z_b = (const float*)d_in[9];

    const int N = in_sizes[0] / C_M;          // 768
    float* out_m = (float*)d_out;
    float* out_z = out_m + (long long)N * C_M;

    const long long total = (long long)N * N;
    const int G = 2048;                        // 8 blocks/CU, 32 waves/CU
    const long long S = (long long)G * 8;      // 16384 slots
    const int mB = (N + 3) / 4;

    // uniform path: every slot gets exactly total/S phases, unroll 4, no tail
    if (total % S == 0 && (total / S) % 4 == 0 && G >= mB) {
        const int phases = (int)(total / S);
        const int di  = (int)(S / N);
        const int rem = (int)(S % N);
        fused_occ<<<G, 256, 0, stream>>>(m, ln_m_w, ln_m_b, out_m, N,
                                         z, x, lin_w, lin_b, ln_z_w, ln_z_b,
                                         out_z, N, phases, di, rem);
    } else {
        int g = 2048;
        if (g < mB) g = mB;
        fused_generic<<<g, 256, 0, stream>>>(m, ln_m_w, ln_m_b, out_m, N,
                                             z, x, lin_w, lin_b, ln_z_w, ln_z_b,
                                             out_z, N);
    }
}

// Round 7
// 105.234 us; speedup vs baseline: 3.5359x; 1.4240x over previous
//
#include <hip/hip_runtime.h>

#define LN_EPS 1e-5f
#define C_M 256
#define C_Z 128
#define NO_BINS 15
#define MAX_PH 64

typedef float f4 __attribute__((ext_vector_type(4)));

__device__ __forceinline__ f4 f4zero() { f4 t = {0.f, 0.f, 0.f, 0.f}; return t; }

// one-hot bin index (or -1); strict inequalities; numpy f32 op order (no FMA)
__device__ __forceinline__ signed char bin_calc(const float* __restrict__ x,
                                                int i, int j)
{
    const float dx = x[3 * i + 0] - x[3 * j + 0];
    const float dy = x[3 * i + 1] - x[3 * j + 1];
    const float dz = x[3 * i + 2] - x[3 * j + 2];
    const float d = __fadd_rn(__fadd_rn(__fmul_rn(dx, dx), __fmul_rn(dy, dy)),
                              __fmul_rn(dz, dz));
    int cnt = 0;
#pragma unroll
    for (int k = 0; k < NO_BINS; ++k) {
        const float bk = 3.25f + 1.25f * (float)k;
        cnt += (d > bk * bk) ? 1 : 0;
    }
    bool valid = (cnt > 0) && (d < 1e8f);
    if (valid && cnt < NO_BINS) {
        // boundary equality d == sq[cnt] zeroes the one-hot (strict ineq.)
        const float bc = 3.25f + 1.25f * (float)cnt;
        valid = (d != bc * bc);
    }
    return valid ? (signed char)(cnt - 1) : (signed char)(-1);
}

__device__ __forceinline__ void ln_stats(const f4 v, float& s, float& s2)
{
    s  = v.x + v.y + v.z + v.w;
    s2 = v.x * v.x + v.y * v.y + v.z * v.z + v.w * v.w;
}

// ---- fused kernel: grid = 2N blocks, j slot-constant, bins precomputed ----
// slot = bid*8+half in [0,16N); rows r = slot + t*16N, t in [0,phases)
// i = slot/N + 16t, j = slot%N. Bins for all (half,t) live in LDS.
__global__ __launch_bounds__(256, 6) void fused_binlds(
    const float* __restrict__ m, const float* __restrict__ ln_m_w,
    const float* __restrict__ ln_m_b, float* __restrict__ out_m, int m_rows,
    const float* __restrict__ z, const float* __restrict__ x,
    const float* __restrict__ lin_w, const float* __restrict__ lin_b,
    const float* __restrict__ ln_z_w, const float* __restrict__ ln_z_b,
    float* __restrict__ out_z, int N, int phases)
{
    __shared__ float lw[NO_BINS * C_Z];          // transposed: [bin][c]
    __shared__ signed char binss[MAX_PH * 8];    // [t][half]
    const int tid = threadIdx.x;
    for (int t = tid; t < NO_BINS * C_Z; t += 256) {
        const int c = t / NO_BINS;
        const int bin = t - c * NO_BINS;
        lw[bin * C_Z + c] = lin_w[t];
    }
    // per-block bins: idx = t*8 + h, parallel over all threads (~2 each)
    for (int idx = tid; idx < phases * 8; idx += 256) {
        const int h = idx & 7;
        const int t = idx >> 3;
        const int slot = (int)blockIdx.x * 8 + h;
        const int bi0 = slot / N;
        const int bj  = slot - bi0 * N;
        binss[idx] = bin_calc(x, bi0 + 16 * t, bj);
    }
    __syncthreads();

    // ---- m LayerNorm: first ceil(m_rows/4) blocks, one wave per row ----
    if ((int)blockIdx.x < ((m_rows + 3) >> 2)) {
        const int wid    = tid >> 6;
        const int lane64 = tid & 63;
        const int row    = blockIdx.x * 4 + wid;
        if (row < m_rows) {
            const f4 v = reinterpret_cast<const f4*>(m + (long long)row * C_M)[lane64];
            float s, s2; ln_stats(v, s, s2);
#pragma unroll
            for (int msk = 1; msk < 64; msk <<= 1) {
                s  += __shfl_xor(s,  msk);
                s2 += __shfl_xor(s2, msk);
            }
            const float mu  = s * (1.0f / C_M);
            const float inv = rsqrtf(s2 * (1.0f / C_M) - mu * mu + LN_EPS);
            const f4 wv = reinterpret_cast<const f4*>(ln_m_w)[lane64];
            const f4 bv = reinterpret_cast<const f4*>(ln_m_b)[lane64];
            f4 o = (v - mu) * inv * wv + bv;
            reinterpret_cast<f4*>(out_m + (long long)row * C_M)[lane64] = o;
        }
    }

    // ---- z loop: 4-row phases; only z traffic in the vmcnt queue ----
    const int half = tid >> 5;
    const int lane = tid & 31;

    const f4 wv = reinterpret_cast<const f4*>(ln_z_w)[lane];
    f4 bv = reinterpret_cast<const f4*>(ln_z_b)[lane];
    bv += reinterpret_cast<const f4*>(lin_b)[lane];   // fold lin_b

    const int slot = (int)blockIdx.x * 8 + half;      // [0, 16N)
    const long long S = (long long)N * 16;            // rows per phase

    long long r = slot;
    for (int p = 0; p < phases; p += 4) {
        const long long r0 = r, r1 = r + S, r2 = r + 2 * S, r3 = r + 3 * S;

        const f4 v0 = reinterpret_cast<const f4*>(z + r0 * C_Z)[lane];
        const f4 v1 = reinterpret_cast<const f4*>(z + r1 * C_Z)[lane];
        const f4 v2 = reinterpret_cast<const f4*>(z + r2 * C_Z)[lane];
        const f4 v3 = reinterpret_cast<const f4*>(z + r3 * C_Z)[lane];

        const int b0 = (int)binss[(p + 0) * 8 + half];   // broadcast LDS byte
        const int b1 = (int)binss[(p + 1) * 8 + half];
        const int b2 = (int)binss[(p + 2) * 8 + half];
        const int b3 = (int)binss[(p + 3) * 8 + half];

        f4 e0 = f4zero(), e1 = f4zero(), e2 = f4zero(), e3 = f4zero();
        if (b0 >= 0) e0 = reinterpret_cast<const f4*>(lw + b0 * C_Z)[lane];
        if (b1 >= 0) e1 = reinterpret_cast<const f4*>(lw + b1 * C_Z)[lane];
        if (b2 >= 0) e2 = reinterpret_cast<const f4*>(lw + b2 * C_Z)[lane];
        if (b3 >= 0) e3 = reinterpret_cast<const f4*>(lw + b3 * C_Z)[lane];

        float s0, q0, s1, q1, s2, q2, s3, q3;
        ln_stats(v0, s0, q0); ln_stats(v1, s1, q1);
        ln_stats(v2, s2, q2); ln_stats(v3, s3, q3);
#pragma unroll
        for (int msk = 1; msk < 32; msk <<= 1) {   // stays within 32-lane group
            s0 += __shfl_xor(s0, msk); q0 += __shfl_xor(q0, msk);
            s1 += __shfl_xor(s1, msk); q1 += __shfl_xor(q1, msk);
            s2 += __shfl_xor(s2, msk); q2 += __shfl_xor(q2, msk);
            s3 += __shfl_xor(s3, msk); q3 += __shfl_xor(q3, msk);
        }
        const float mu0 = s0 * (1.0f / C_Z), iv0 = rsqrtf(q0 * (1.0f / C_Z) - mu0 * mu0 + LN_EPS);
        const float mu1 = s1 * (1.0f / C_Z), iv1 = rsqrtf(q1 * (1.0f / C_Z) - mu1 * mu1 + LN_EPS);
        const float mu2 = s2 * (1.0f / C_Z), iv2 = rsqrtf(q2 * (1.0f / C_Z) - mu2 * mu2 + LN_EPS);
        const float mu3 = s3 * (1.0f / C_Z), iv3 = rsqrtf(q3 * (1.0f / C_Z) - mu3 * mu3 + LN_EPS);

        f4 o0 = (v0 - mu0) * iv0 * wv + bv + e0;
        f4 o1 = (v1 - mu1) * iv1 * wv + bv + e1;
        f4 o2 = (v2 - mu2) * iv2 * wv + bv + e2;
        f4 o3 = (v3 - mu3) * iv3 * wv + bv + e3;
        __builtin_nontemporal_store(o0, reinterpret_cast<f4*>(out_z + r0 * C_Z) + lane);
        __builtin_nontemporal_store(o1, reinterpret_cast<f4*>(out_z + r1 * C_Z) + lane);
        __builtin_nontemporal_store(o2, reinterpret_cast<f4*>(out_z + r2 * C_Z) + lane);
        __builtin_nontemporal_store(o3, reinterpret_cast<f4*>(out_z + r3 * C_Z) + lane);

        r += 4 * S;
    }
}

// ---- generic fallback (any N) ----
__device__ __forceinline__ int bin_of(const float* __restrict__ x,
                                      const float* sqb, int i, int j)
{
    const float dx = x[3 * i + 0] - x[3 * j + 0];
    const float dy = x[3 * i + 1] - x[3 * j + 1];
    const float dz = x[3 * i + 2] - x[3 * j + 2];
    const float d = __fadd_rn(__fadd_rn(__fmul_rn(dx, dx), __fmul_rn(dy, dy)),
                              __fmul_rn(dz, dz));
    int cnt = 0;
#pragma unroll
    for (int k = 0; k < NO_BINS; ++k) {
        const float bk = 3.25f + 1.25f * (float)k;
        cnt += (d > bk * bk) ? 1 : 0;
    }
    return ((cnt > 0) && (d < 1e8f) && (d != sqb[cnt])) ? cnt - 1 : -1;
}

__global__ __launch_bounds__(256) void fused_generic(
    const float* __restrict__ m, const float* __restrict__ ln_m_w,
    const float* __restrict__ ln_m_b, float* __restrict__ out_m, int m_rows,
    const float* __restrict__ z, const float* __restrict__ x,
    const float* __restrict__ lin_w, const float* __restrict__ lin_b,
    const float* __restrict__ ln_z_w, const float* __restrict__ ln_z_b,
    float* __restrict__ out_z, int N)
{
    __shared__ float lw[NO_BINS * C_Z];
    __shared__ float sqb[16];
    const int tid = threadIdx.x;
    for (int t = tid; t < NO_BINS * C_Z; t += 256) {
        const int c = t / NO_BINS;
        const int bin = t - c * NO_BINS;
        lw[bin * C_Z + c] = lin_w[t];
    }
    if (tid < 16) {
        const float bk = 3.25f + 1.25f * (float)tid;
        sqb[tid] = (tid < NO_BINS) ? bk * bk : -1.0f;
    }
    __syncthreads();

    if ((int)blockIdx.x < ((m_rows + 3) >> 2)) {
        const int wid    = tid >> 6;
        const int lane64 = tid & 63;
        const int row    = blockIdx.x * 4 + wid;
        if (row < m_rows) {
            const f4 v = reinterpret_cast<const f4*>(m + (long long)row * C_M)[lane64];
            float s, s2; ln_stats(v, s, s2);
#pragma unroll
            for (int msk = 1; msk < 64; msk <<= 1) {
                s  += __shfl_xor(s,  msk);
                s2 += __shfl_xor(s2, msk);
            }
            const float mu  = s * (1.0f / C_M);
            const float inv = rsqrtf(s2 * (1.0f / C_M) - mu * mu + LN_EPS);
            const f4 wv = reinterpret_cast<const f4*>(ln_m_w)[lane64];
            const f4 bv = reinterpret_cast<const f4*>(ln_m_b)[lane64];
            f4 o = (v - mu) * inv * wv + bv;
            reinterpret_cast<f4*>(out_m + (long long)row * C_M)[lane64] = o;
        }
    }

    const int half = tid >> 5;
    const int lane = tid & 31;
    const f4 wv = reinterpret_cast<const f4*>(ln_z_w)[lane];
    f4 bv = reinterpret_cast<const f4*>(ln_z_b)[lane];
    bv += reinterpret_cast<const f4*>(lin_b)[lane];

    const long long total  = (long long)N * N;
    const long long stride = (long long)gridDim.x * 8;
    for (long long r = (long long)blockIdx.x * 8 + half; r < total; r += stride) {
        const int i = (int)(r / N);
        const int j = (int)(r - (long long)i * N);
        const f4 v = reinterpret_cast<const f4*>(z + r * C_Z)[lane];
        const int bin = bin_of(x, sqb, i, j);
        f4 e = f4zero();
        if (bin >= 0) e = reinterpret_cast<const f4*>(lw + bin * C_Z)[lane];
        float s, s2; ln_stats(v, s, s2);
#pragma unroll
        for (int msk = 1; msk < 32; msk <<= 1) {
            s  += __shfl_xor(s,  msk);
            s2 += __shfl_xor(s2, msk);
        }
        const float mu  = s * (1.0f / C_Z);
        const float inv = rsqrtf(s2 * (1.0f / C_Z) - mu * mu + LN_EPS);
        f4 o = (v - mu) * inv * wv + bv + e;
        __builtin_nontemporal_store(o, reinterpret_cast<f4*>(out_z + r * C_Z) + lane);
    }
}

extern "C" void kernel_launch(void* const* d_in, const int* in_sizes, int n_in,
                              void* d_out, int out_size, void* d_ws, size_t ws_size,
                              hipStream_t stream) {
    const float* m      = (const float*)d_in[0];
    const float* z      = (const float*)d_in[1];
    const float* x      = (const float*)d_in[2];
    // d_in[3] = seqs (unused)
    const float* lin_w  = (const float*)d_in[4];
    const float* lin_b  = (const float*)d_in[5];
    const float* ln_m_w = (const float*)d_in[6];
    const float* ln_m_b = (const float*)d_in[7];
    const float* ln_z_w = (const float*)d_in[8];
    const float* ln_z_b = (const float*)d_in[9];

    const int N = in_sizes[0] / C_M;          // 768
    float* out_m = (float*)d_out;
    float* out_z = out_m + (long long)N * C_M;

    const int mB = (N + 3) / 4;
    const int phases = N / 16;                // rows per slot

    if ((N % 16) == 0 && phases <= MAX_PH && (phases % 4) == 0 && 2 * N >= mB) {
        // grid = 2N blocks (6/CU at N=768, co-resident), j slot-constant
        fused_binlds<<<2 * N, 256, 0, stream>>>(m, ln_m_w, ln_m_b, out_m, N,
                                                z, x, lin_w, lin_b, ln_z_w, ln_z_b,
                                                out_z, N, phases);
    } else {
        int g = 2048;
        if (g < mB) g = mB;
        fused_generic<<<g, 256, 0, stream>>>(m, ln_m_w, ln_m_b, out_m, N,
                                             z, x, lin_w, lin_b, ln_z_w, ln_z_b,
                                             out_z, N);
    }
}